// Round 3
// baseline (228.058 us; speedup 1.0000x reference)
//
#include <hip/hip_runtime.h>
#include <stdint.h>
#include <stddef.h>

#define DEV __device__ __forceinline__

typedef __attribute__((ext_vector_type(4))) float f32x4;
typedef __attribute__((ext_vector_type(8))) short bf16x8;

union FragU { bf16x8 f; uint32_t u[4]; };

DEV uint32_t pk_bf16(float a, float b) {
  uint32_t d;
  asm("v_cvt_pk_bf16_f32 %0, %1, %2" : "=v"(d) : "v"(a), "v"(b));
  return d;
}

DEV uint16_t f2bf(float x) {  // round-to-nearest-even
  uint32_t u = __float_as_uint(x);
  u += 0x7fffu + ((u >> 16) & 1u);
  return (uint16_t)(u >> 16);
}

// ---------------------------------------------------------------------------
// K_pre: blocks 0..2: transpose Wq/Wk/Wv; block 3: Ww1/Ww2 -> bf16 in
//        MFMA-FRAGMENT order; block 4: analytic BN1 -> a1
// ---------------------------------------------------------------------------
__launch_bounds__(256)
__global__ void kpre(const float* __restrict__ Wq, const float* __restrict__ Wk,
                     const float* __restrict__ Wv, const float* __restrict__ Ww1,
                     const float* __restrict__ Ww2, const float* __restrict__ pos,
                     const float* __restrict__ Wp1, const float* __restrict__ g_p,
                     float* __restrict__ WqT, float* __restrict__ WkT,
                     float* __restrict__ WvT, uint16_t* __restrict__ W1bf,
                     uint16_t* __restrict__ W2bf, float* __restrict__ a1out) {
  const int bid = blockIdx.x, t = threadIdx.x;
  if (bid < 3) {
    const float* src = (bid == 0) ? Wq : ((bid == 1) ? Wk : Wv);
    float* dst = (bid == 0) ? WqT : ((bid == 1) ? WkT : WvT);
    for (int idx = t; idx < 4096; idx += 256) {
      int kk = idx >> 6, c = idx & 63;
      dst[kk * 64 + c] = src[c * 64 + kk];
    }
  } else if (bid == 3) {
    // frag order: idx = ((nt*2+ks)*64 + lane)*8 + e
    for (int idx = t; idx < 8192; idx += 256) {
      const int m = idx >> 12;
      const int r = idx & 4095;
      const int f = r >> 9;
      const int l = (r >> 3) & 63;
      const int e = r & 7;
      const int nt = f >> 1, ks = f & 1, lm = l & 15, lq = l >> 4;
      const int row = 16 * nt + lm, col = 8 * lq + 32 * ks + e;
      const float src = m ? Ww2[row * 64 + col] : Ww1[row * 64 + col];
      (m ? W2bf : W1bf)[r] = f2bf(src);
    }
  } else {
    __shared__ float acc9[2][9];
    __shared__ float red[256][10];
    __shared__ float red2[9][16];
    for (int b = 0; b < 2; ++b) {
      float s[9];
#pragma unroll
      for (int a = 0; a < 9; ++a) s[a] = 0.f;
      for (int r = 0; r < 2; ++r) {
        int i = t + 256 * r;
        const float* p = pos + (size_t)(b * 512 + i) * 3;
        float p0 = p[0], p1 = p[1], p2 = p[2];
        s[0] += p0; s[1] += p1; s[2] += p2;
        s[3] += p0 * p0; s[4] += p0 * p1; s[5] += p0 * p2;
        s[6] += p1 * p1; s[7] += p1 * p2; s[8] += p2 * p2;
      }
#pragma unroll
      for (int a = 0; a < 9; ++a) red[t][a] = s[a];
      __syncthreads();
      if (t < 144) {
        const int a = t >> 4, p = t & 15;
        float v = 0.f;
#pragma unroll
        for (int q = 0; q < 16; ++q) v += red[p * 16 + q][a];
        red2[a][p] = v;
      }
      __syncthreads();
      if (t < 9) {
        float v = 0.f;
#pragma unroll
        for (int p = 0; p < 16; ++p) v += red2[t][p];
        acc9[b][t] = v;
      }
      __syncthreads();
    }
    if (t == 0) {
      float C[6] = {0.f, 0.f, 0.f, 0.f, 0.f, 0.f};
      const float invM = 1.0f / 524288.0f;
      for (int b = 0; b < 2; ++b) {
        float S0 = acc9[b][0], S1 = acc9[b][1], S2 = acc9[b][2];
        float G00 = acc9[b][3], G01 = acc9[b][4], G02 = acc9[b][5];
        float G11 = acc9[b][6], G12 = acc9[b][7], G22 = acc9[b][8];
        C[0] += 1024.f * G00 - 2.f * S0 * S0;
        C[1] += 1024.f * G01 - 2.f * S0 * S1;
        C[2] += 1024.f * G02 - 2.f * S0 * S2;
        C[3] += 1024.f * G11 - 2.f * S1 * S1;
        C[4] += 1024.f * G12 - 2.f * S1 * S2;
        C[5] += 1024.f * G22 - 2.f * S2 * S2;
      }
      for (int a = 0; a < 6; ++a) C[a] *= invM;
      for (int tt = 0; tt < 3; ++tt) {
        float w0 = Wp1[tt * 3 + 0], w1 = Wp1[tt * 3 + 1], w2 = Wp1[tt * 3 + 2];
        float var = w0 * w0 * C[0] + w1 * w1 * C[3] + w2 * w2 * C[5]
                  + 2.f * (w0 * w1 * C[1] + w0 * w2 * C[2] + w1 * w2 * C[4]);
        a1out[tt] = g_p[tt] * rsqrtf(var + 1e-5f);
      }
      a1out[3] = 0.f;
    }
  }
}

// ---------------------------------------------------------------------------
// K0: q/k row-major, v (+bp2 folded) transposed vT[b][c][n], hpa
// ---------------------------------------------------------------------------
__launch_bounds__(256)
__global__ void k0(const float* __restrict__ cf, const float* __restrict__ pos,
                   const float* __restrict__ WqT, const float* __restrict__ WkT,
                   const float* __restrict__ WvT, const float* __restrict__ bq,
                   const float* __restrict__ bk, const float* __restrict__ bv,
                   const float* __restrict__ a1, const float* __restrict__ Wp1,
                   const float* __restrict__ bp2,
                   float* __restrict__ qo, float* __restrict__ ko,
                   float* __restrict__ vT, float* __restrict__ hpa) {
  __shared__ float cfl[4][64];
  const int t = threadIdx.x;
  const int r0 = blockIdx.x * 4;
  cfl[t >> 6][t & 63] = cf[(size_t)(r0 + (t >> 6)) * 64 + (t & 63)];
  __syncthreads();
  const int rr = t >> 6, c = t & 63;
  const int bn = r0 + rr;
  float aq = bq[c], ak = bk[c], av = bv[c] + bp2[c];
  for (int kk = 0; kk < 64; ++kk) {
    float f = cfl[rr][kk];
    aq = fmaf(f, WqT[kk * 64 + c], aq);
    ak = fmaf(f, WkT[kk * 64 + c], ak);
    av = fmaf(f, WvT[kk * 64 + c], av);
  }
  qo[(size_t)bn * 64 + c] = aq;
  ko[(size_t)bn * 64 + c] = ak;
  vT[((size_t)(bn >> 9) * 64 + c) * 512 + (bn & 511)] = av;
  if (t < 16) {
    int rr2 = t >> 2, tt = t & 3;
    int bn2 = r0 + rr2;
    float h = 0.f;
    if (tt < 3) {
      const float* p = pos + (size_t)bn2 * 3;
      h = a1[tt] * (Wp1[tt * 3 + 0] * p[0] + Wp1[tt * 3 + 1] * p[1] + Wp1[tt * 3 + 2] * p[2]);
    }
    hpa[bn2 * 4 + tt] = h;
  }
}

// ---------------------------------------------------------------------------
// K1n: bid<32: 3-channel pair pass (R/C sums + M moments); bid 32/33:
//      per-batch N-pass moments of u=q+bp2 and k.
// ---------------------------------------------------------------------------
__launch_bounds__(256)
__global__ void k1n(const float* __restrict__ hpa, const float* __restrict__ b_p,
                    const float* __restrict__ q, const float* __restrict__ k,
                    const float* __restrict__ bp2,
                    float* __restrict__ Rw, float* __restrict__ Cw,
                    float* __restrict__ Mpart, float* __restrict__ SN) {
  const int bid = blockIdx.x, t = threadIdx.x;
  if (bid < 32) {
    const int s = bid >> 4, b = (bid >> 3) & 1, chunk = bid & 7;
    __shared__ __align__(16) f32x4 X[512];
    __shared__ float redr[64][4][4];
    __shared__ float mred[256][6];
    __shared__ float mred2[64][6];
    for (int r = 0; r < 2; ++r) {
      int row = t + 256 * r;
      f32x4 v = *(const f32x4*)(hpa + (size_t)(b * 512 + row) * 4);
      if (s) { v.x = -v.x; v.y = -v.y; v.z = -v.z; }
      X[row] = v;
    }
    __syncthreads();
    const int al = t >> 2, qr = t & 3;
    const int a = chunk * 64 + al;
    const f32x4 xa = X[a];
    const float base0 = xa.x + b_p[0], base1 = xa.y + b_p[1], base2 = xa.z + b_p[2];
    float r0 = 0, r1 = 0, r2 = 0;
    float m00 = 0, m01 = 0, m02 = 0, m11 = 0, m12 = 0, m22 = 0;
    for (int jj = qr * 128; jj < qr * 128 + 128; ++jj) {
      const f32x4 xj = X[jj];
      const float h0 = fmaxf(0.f, base0 - xj.x);
      const float h1 = fmaxf(0.f, base1 - xj.y);
      const float h2 = fmaxf(0.f, base2 - xj.z);
      r0 += h0; r1 += h1; r2 += h2;
      if (s == 0) {
        m00 = fmaf(h0, h0, m00); m01 = fmaf(h0, h1, m01); m02 = fmaf(h0, h2, m02);
        m11 = fmaf(h1, h1, m11); m12 = fmaf(h1, h2, m12); m22 = fmaf(h2, h2, m22);
      }
    }
    redr[al][qr][0] = r0; redr[al][qr][1] = r1; redr[al][qr][2] = r2; redr[al][qr][3] = 0.f;
    mred[t][0] = m00; mred[t][1] = m01; mred[t][2] = m02;
    mred[t][3] = m11; mred[t][4] = m12; mred[t][5] = m22;
    __syncthreads();
    if (t < 64) {
      float sx = 0, sy = 0, sz = 0;
#pragma unroll
      for (int p = 0; p < 4; ++p) { sx += redr[t][p][0]; sy += redr[t][p][1]; sz += redr[t][p][2]; }
      float* dst = (s ? Cw : Rw) + (size_t)(b * 512 + chunk * 64 + t) * 4;
      dst[0] = sx; dst[1] = sy; dst[2] = sz; dst[3] = 0.f;
      if (s == 0) {
#pragma unroll
        for (int cc = 0; cc < 6; ++cc)
          mred2[t][cc] = mred[t][cc] + mred[t + 64][cc] + mred[t + 128][cc] + mred[t + 192][cc];
      }
    }
    __syncthreads();
    if (s == 0 && t < 6) {
      float m = 0.f;
      for (int p = 0; p < 64; ++p) m += mred2[p][t];
      Mpart[bid * 8 + t] = m;
    }
  } else {
    const int b = bid - 32;
    __shared__ float redn[256][4];
    const int c = t & 63, g = t >> 6;
    float su = 0, su2 = 0, sk = 0, sk2 = 0;
    const float bp = bp2[c];
    for (int i = g * 128; i < g * 128 + 128; ++i) {
      const float uq = q[(size_t)(b * 512 + i) * 64 + c] + bp;
      const float kv = k[(size_t)(b * 512 + i) * 64 + c];
      su += uq; su2 = fmaf(uq, uq, su2);
      sk += kv; sk2 = fmaf(kv, kv, sk2);
    }
    redn[t][0] = su; redn[t][1] = su2; redn[t][2] = sk; redn[t][3] = sk2;
    __syncthreads();
    if (t < 64) {
      float a0 = 0, a1 = 0, a2 = 0, a3 = 0;
#pragma unroll
      for (int p = 0; p < 4; ++p) {
        a0 += redn[t + 64 * p][0]; a1 += redn[t + 64 * p][1];
        a2 += redn[t + 64 * p][2]; a3 += redn[t + 64 * p][3];
      }
      SN[(b * 4 + 0) * 64 + t] = a0;
      SN[(b * 4 + 1) * 64 + t] = a1;
      SN[(b * 4 + 2) * 64 + t] = a2;
      SN[(b * 4 + 3) * 64 + t] = a3;
    }
  }
}

// ---------------------------------------------------------------------------
// K2n: assemble BN2 stats -> a2, be2, PtT. 1024 threads; ur/kc linear in b.
// ---------------------------------------------------------------------------
__launch_bounds__(1024)
__global__ void k2n(const float* __restrict__ q, const float* __restrict__ k,
                    const float* __restrict__ bp2,
                    const float* __restrict__ Rw, const float* __restrict__ Cw,
                    const float* __restrict__ Mpart, const float* __restrict__ SN,
                    const float* __restrict__ g_w, const float* __restrict__ b_w,
                    const float* __restrict__ Wp2,
                    float* __restrict__ a2o, float* __restrict__ be2o,
                    float* __restrict__ PtT) {
  const int t = threadIdx.x;
  const int c = t & 63, g = t >> 6;  // g: 0..15
  __shared__ float red[1024][6];
  __shared__ float shs[16][3];
  __shared__ float Mf[6];
  __shared__ float Shf[3];
  float ur0 = 0, ur1 = 0, ur2 = 0, kc0 = 0, kc1 = 0, kc2 = 0;
  float shp0 = 0, shp1 = 0, shp2 = 0;
  const float bp = bp2[c];
  for (int it = 0; it < 64; ++it) {
    const size_t row = (size_t)(g * 64 + it);
    const float uq = q[row * 64 + c] + bp;
    const float kv = k[row * 64 + c];
    const f32x4 rv = *(const f32x4*)(Rw + row * 4);
    const f32x4 cv = *(const f32x4*)(Cw + row * 4);
    ur0 = fmaf(uq, rv.x, ur0); ur1 = fmaf(uq, rv.y, ur1); ur2 = fmaf(uq, rv.z, ur2);
    kc0 = fmaf(kv, cv.x, kc0); kc1 = fmaf(kv, cv.y, kc1); kc2 = fmaf(kv, cv.z, kc2);
    if (c == 0) { shp0 += rv.x; shp1 += rv.y; shp2 += rv.z; }
  }
  red[t][0] = ur0; red[t][1] = ur1; red[t][2] = ur2;
  red[t][3] = kc0; red[t][4] = kc1; red[t][5] = kc2;
  if (c == 0) { shs[g][0] = shp0; shs[g][1] = shp1; shs[g][2] = shp2; }
  __syncthreads();
  if (t < 6) {
    float m = 0.f;
    for (int p = 0; p < 16; ++p) m += Mpart[p * 8 + t];
    Mf[t] = m;
  }
  if (t >= 64 && t < 67) {
    const int tt = t - 64;
    float v = 0.f;
    for (int p = 0; p < 16; ++p) v += shs[p][tt];
    Shf[tt] = v;
  }
  __syncthreads();
  if (t < 64) {
    float URd0 = 0, URd1 = 0, URd2 = 0;  // sum over b of (UR - KC)
#pragma unroll
    for (int p = 0; p < 16; ++p) {
      URd0 += red[t + 64 * p][0] - red[t + 64 * p][3];
      URd1 += red[t + 64 * p][1] - red[t + 64 * p][4];
      URd2 += red[t + 64 * p][2] - red[t + 64 * p][5];
    }
    const float P0t = Wp2[t * 3 + 0], P1t = Wp2[t * 3 + 1], P2t = Wp2[t * 3 + 2];
    const float Nf = 512.f, invM = 1.f / 524288.f;
    float S1 = 0.f, Q2 = 0.f;
#pragma unroll
    for (int b = 0; b < 2; ++b) {
      const float Su = SN[(b * 4 + 0) * 64 + t];
      const float Su2 = SN[(b * 4 + 1) * 64 + t];
      const float Sk = SN[(b * 4 + 2) * 64 + t];
      const float Sk2 = SN[(b * 4 + 3) * 64 + t];
      S1 += Nf * (Su - Sk);
      Q2 += Nf * Su2 - 2.f * Su * Sk + Nf * Sk2;
    }
    const float Xc = P0t * URd0 + P1t * URd1 + P2t * URd2;
    S1 += P0t * Shf[0] + P1t * Shf[1] + P2t * Shf[2];
    const float Hm = P0t * P0t * Mf[0] + 2.f * P0t * P1t * Mf[1] + 2.f * P0t * P2t * Mf[2]
                   + P1t * P1t * Mf[3] + 2.f * P1t * P2t * Mf[4] + P2t * P2t * Mf[5];
    const float E1 = S1 * invM;
    const float E2 = (Q2 + 2.f * Xc + Hm) * invM;
    const float var = E2 - E1 * E1;
    const float rstd = rsqrtf(var + 1e-5f);
    const float A2 = g_w[t] * rstd;
    a2o[t] = A2;
    be2o[t] = b_w[t] - E1 * A2;
    PtT[0 * 64 + t] = A2 * P0t;
    PtT[1 * 64 + t] = A2 * P1t;
    PtT[2 * 64 + t] = A2 * P2t;
  }
}

// ---------------------------------------------------------------------------
// K3: fused main. No-max softmax, frag-linear weight LDS, reg-hoisted
// stage-A constants, kv prefetch.
// ---------------------------------------------------------------------------
__launch_bounds__(256, 3)
__global__ void k3_main(const float* __restrict__ q, const float* __restrict__ kk_,
                        const float* __restrict__ vT, const float* __restrict__ hpa,
                        const float* __restrict__ a2g, const float* __restrict__ be2g,
                        const float* __restrict__ PtTg,
                        const uint16_t* __restrict__ W1bf, const uint16_t* __restrict__ W2bf,
                        const float* __restrict__ bp2, const float* __restrict__ Wp2,
                        const float* __restrict__ b_p, const float* __restrict__ bw1g,
                        const float* __restrict__ bw2g, float* __restrict__ out) {
  const int bid = blockIdx.x;
  const int b = bid >> 9, i = bid & 511;
  const int t = threadIdx.x;
  const int wid = t >> 6, l = t & 63;
  const int lm = l & 15, lq = l >> 4;

  __shared__ __align__(16) uint16_t W1l[4096];
  __shared__ __align__(16) uint16_t W2l[4096];
  __shared__ __align__(16) uint16_t H2[4][16][72];
  __shared__ __align__(16) float comb[4][64][2];

  // stage weights (frag-linear, 32B/thread/matrix)
  {
    *(bf16x8*)(&W1l[t * 16])     = *(const bf16x8*)(W1bf + t * 16);
    *(bf16x8*)(&W1l[t * 16 + 8]) = *(const bf16x8*)(W1bf + t * 16 + 8);
    *(bf16x8*)(&W2l[t * 16])     = *(const bf16x8*)(W2bf + t * 16);
    *(bf16x8*)(&W2l[t * 16 + 8]) = *(const bf16x8*)(W2bf + t * 16 + 8);
  }

  // per-lane stage-A constants: c = 32*ks + 8*lq + {0..7}
  f32x4 P0A[2][2], a2A[2][2], t0A[2][2], t1A[2][2], t2A[2][2];
#pragma unroll
  for (int ks = 0; ks < 2; ++ks) {
    const int c0 = 32 * ks + 8 * lq;
#pragma unroll
    for (int h = 0; h < 2; ++h) {
      const int c = c0 + 4 * h;
      const f32x4 qv = *(const f32x4*)(q + (size_t)(b * 512 + i) * 64 + c);
      const f32x4 a2v = *(const f32x4*)(a2g + c);
      const f32x4 bpv = *(const f32x4*)(bp2 + c);
      const f32x4 bev = *(const f32x4*)(be2g + c);
      f32x4 p0;
#pragma unroll
      for (int e = 0; e < 4; ++e) p0[e] = fmaf(a2v[e], qv[e] + bpv[e], bev[e]);
      P0A[ks][h] = p0;
      a2A[ks][h] = a2v;
      t0A[ks][h] = *(const f32x4*)(PtTg + 0 * 64 + c);
      t1A[ks][h] = *(const f32x4*)(PtTg + 1 * 64 + c);
      t2A[ks][h] = *(const f32x4*)(PtTg + 2 * 64 + c);
    }
  }

  const f32x4 hi = *(const f32x4*)(hpa + (size_t)(b * 512 + i) * 4);
  const float bb0 = b_p[0], bb1 = b_p[1], bb2 = b_p[2];
  const float LOG2E = 1.4426950408889634f;

  float bw1r[4], bw2l[4], wpa[4], wpb[4], wpc[4];
#pragma unroll
  for (int nt = 0; nt < 4; ++nt) {
    const int c = 16 * nt + lm;
    bw1r[nt] = bw1g[c];
    bw2l[nt] = bw2g[c] * LOG2E;
    wpa[nt] = Wp2[c * 3 + 0];
    wpb[nt] = Wp2[c * 3 + 1];
    wpc[nt] = Wp2[c * 3 + 2];
  }

  float l_[4] = {0.f, 0.f, 0.f, 0.f};
  float acc_[4] = {0.f, 0.f, 0.f, 0.f};

  __syncthreads();

  const float* kbase = kk_ + (size_t)(b * 512) * 64;
  const float* hbase = hpa + (size_t)(b * 512) * 4;
  const float* vTb = vT + (size_t)b * 64 * 512;

  // prefetch kv for it=0
  f32x4 kvP[2][2];
  {
    const int j = wid * 16 + lm;
#pragma unroll
    for (int ks = 0; ks < 2; ++ks) {
      kvP[ks][0] = *(const f32x4*)(kbase + (size_t)j * 64 + 32 * ks + 8 * lq);
      kvP[ks][1] = *(const f32x4*)(kbase + (size_t)j * 64 + 32 * ks + 8 * lq + 4);
    }
  }

#pragma unroll
  for (int it = 0; it < 8; ++it) {
    const int jb = it * 64 + wid * 16;
    const int j = jb + lm;
    const int j2 = jb + 4 * lq;

    // prefetch next iteration's k row
    f32x4 kvN[2][2];
    if (it < 7) {
      const int jn = jb + 64 + lm;
#pragma unroll
      for (int ks = 0; ks < 2; ++ks) {
        kvN[ks][0] = *(const f32x4*)(kbase + (size_t)jn * 64 + 32 * ks + 8 * lq);
        kvN[ks][1] = *(const f32x4*)(kbase + (size_t)jn * 64 + 32 * ks + 8 * lq + 4);
      }
    }

    // other per-iter loads (L1/L2-hot)
    const f32x4 hj = *(const f32x4*)(hbase + j * 4);
    f32x4 hjr[4];
#pragma unroll
    for (int r = 0; r < 4; ++r) hjr[r] = *(const f32x4*)(hbase + (j2 + r) * 4);
    f32x4 vv[4];
#pragma unroll
    for (int nt = 0; nt < 4; ++nt)
      vv[nt] = *(const f32x4*)(vTb + (size_t)(16 * nt + lm) * 512 + j2);

    // ---- stage A ----
    const float h0 = fmaxf(0.f, hi.x - hj.x + bb0);
    const float h1 = fmaxf(0.f, hi.y - hj.y + bb1);
    const float h2v = fmaxf(0.f, hi.z - hj.z + bb2);

    FragU A1[2];
#pragma unroll
    for (int ks = 0; ks < 2; ++ks) {
      float x[8];
#pragma unroll
      for (int e = 0; e < 8; ++e) {
        const int hh = e >> 2, e4 = e & 3;
        float xv = P0A[ks][hh][e4] - a2A[ks][hh][e4] * kvP[ks][hh][e4];
        xv = fmaf(t0A[ks][hh][e4], h0, xv);
        xv = fmaf(t1A[ks][hh][e4], h1, xv);
        xv = fmaf(t2A[ks][hh][e4], h2v, xv);
        x[e] = fmaxf(0.f, xv);
      }
      A1[ks].u[0] = pk_bf16(x[0], x[1]);
      A1[ks].u[1] = pk_bf16(x[2], x[3]);
      A1[ks].u[2] = pk_bf16(x[4], x[5]);
      A1[ks].u[3] = pk_bf16(x[6], x[7]);
    }

    // ---- GEMM1 ----
    f32x4 d1[4];
#pragma unroll
    for (int nt = 0; nt < 4; ++nt) {
      FragU b0, b1;
      b0.f = *(const bf16x8*)(&W1l[((nt * 2 + 0) * 64 + l) * 8]);
      b1.f = *(const bf16x8*)(&W1l[((nt * 2 + 1) * 64 + l) * 8]);
      f32x4 z = {0.f, 0.f, 0.f, 0.f};
      z = __builtin_amdgcn_mfma_f32_16x16x32_bf16(A1[0].f, b0.f, z, 0, 0, 0);
      z = __builtin_amdgcn_mfma_f32_16x16x32_bf16(A1[1].f, b1.f, z, 0, 0, 0);
      d1[nt] = z;
    }

    // ---- bias+relu, repack h2 to bf16 LDS (per-wave private) ----
    uint16_t (*h2w)[72] = H2[wid];
#pragma unroll
    for (int nt = 0; nt < 4; ++nt) {
      const float e0 = fmaxf(0.f, d1[nt][0] + bw1r[nt]);
      const float e1 = fmaxf(0.f, d1[nt][1] + bw1r[nt]);
      const float e2 = fmaxf(0.f, d1[nt][2] + bw1r[nt]);
      const float e3 = fmaxf(0.f, d1[nt][3] + bw1r[nt]);
      const uint32_t u01 = pk_bf16(e0, e1);
      const uint32_t u23 = pk_bf16(e2, e3);
      const int col = 16 * nt + lm;
      h2w[4 * lq + 0][col] = (uint16_t)(u01 & 0xffffu);
      h2w[4 * lq + 1][col] = (uint16_t)(u01 >> 16);
      h2w[4 * lq + 2][col] = (uint16_t)(u23 & 0xffffu);
      h2w[4 * lq + 3][col] = (uint16_t)(u23 >> 16);
    }

    FragU A2[2];
    A2[0].f = *(const bf16x8*)(&h2w[lm][8 * lq]);
    A2[1].f = *(const bf16x8*)(&h2w[lm][32 + 8 * lq]);

    // ---- GEMM2 ----
    f32x4 d2[4];
#pragma unroll
    for (int nt = 0; nt < 4; ++nt) {
      FragU b0, b1;
      b0.f = *(const bf16x8*)(&W2l[((nt * 2 + 0) * 64 + l) * 8]);
      b1.f = *(const bf16x8*)(&W2l[((nt * 2 + 1) * 64 + l) * 8]);
      f32x4 z = {0.f, 0.f, 0.f, 0.f};
      z = __builtin_amdgcn_mfma_f32_16x16x32_bf16(A2[0].f, b0.f, z, 0, 0, 0);
      z = __builtin_amdgcn_mfma_f32_16x16x32_bf16(A2[1].f, b1.f, z, 0, 0, 0);
      d2[nt] = z;
    }

    // ---- hr for this lane's 4 output j-rows ----
    float hr0[4], hr1[4], hr2[4];
#pragma unroll
    for (int r = 0; r < 4; ++r) {
      hr0[r] = fmaxf(0.f, hi.x - hjr[r].x + bb0);
      hr1[r] = fmaxf(0.f, hi.y - hjr[r].y + bb1);
      hr2[r] = fmaxf(0.f, hi.z - hjr[r].z + bb2);
    }

    // ---- no-max softmax accumulation ----
#pragma unroll
    for (int nt = 0; nt < 4; ++nt) {
      float p[4], val[4];
#pragma unroll
      for (int r = 0; r < 4; ++r) {
        p[r] = __builtin_amdgcn_exp2f(fmaf(d2[nt][r], LOG2E, bw2l[nt]));
        float v0 = vv[nt][r];
        v0 = fmaf(wpa[nt], hr0[r], v0);
        v0 = fmaf(wpb[nt], hr1[r], v0);
        v0 = fmaf(wpc[nt], hr2[r], v0);
        val[r] = v0;
      }
      l_[nt] += (p[0] + p[1]) + (p[2] + p[3]);
      float a = acc_[nt];
      a = fmaf(p[0], val[0], a);
      a = fmaf(p[1], val[1], a);
      a = fmaf(p[2], val[2], a);
      a = fmaf(p[3], val[3], a);
      acc_[nt] = a;
    }

    // rotate prefetch
    if (it < 7) {
#pragma unroll
      for (int ks = 0; ks < 2; ++ks) {
        kvP[ks][0] = kvN[ks][0];
        kvP[ks][1] = kvN[ks][1];
      }
    }
  }

  // ---- combine: sum over lq groups (linear, no max) ----
#pragma unroll
  for (int nt = 0; nt < 4; ++nt) {
    l_[nt] += __shfl_xor(l_[nt], 16);
    acc_[nt] += __shfl_xor(acc_[nt], 16);
    l_[nt] += __shfl_xor(l_[nt], 32);
    acc_[nt] += __shfl_xor(acc_[nt], 32);
  }
  if (lq == 0) {
#pragma unroll
    for (int nt = 0; nt < 4; ++nt) {
      comb[wid][16 * nt + lm][0] = l_[nt];
      comb[wid][16 * nt + lm][1] = acc_[nt];
    }
  }
  __syncthreads();
  if (t < 64) {
    float L = 0.f, A = 0.f;
#pragma unroll
    for (int w = 0; w < 4; ++w) {
      L += comb[w][t][0];
      A += comb[w][t][1];
    }
    out[(size_t)(b * 512 + i) * 64 + t] = A / L;
  }
}

// ---------------------------------------------------------------------------
extern "C" void kernel_launch(void* const* d_in, const int* in_sizes, int n_in,
                              void* d_out, int out_size, void* d_ws, size_t ws_size,
                              hipStream_t stream) {
  (void)in_sizes; (void)n_in; (void)out_size; (void)ws_size;
  const float* pos = (const float*)d_in[0];
  const float* cf  = (const float*)d_in[1];
  const float* Wq  = (const float*)d_in[2];
  const float* bq  = (const float*)d_in[3];
  const float* Wk  = (const float*)d_in[4];
  const float* bk  = (const float*)d_in[5];
  const float* Wv  = (const float*)d_in[6];
  const float* bv  = (const float*)d_in[7];
  const float* Wp1 = (const float*)d_in[8];
  // d_in[9] = bp1: cancels analytically (gamma1 == b_p exactly)
  const float* g_p = (const float*)d_in[10];
  const float* b_p = (const float*)d_in[11];
  const float* Wp2 = (const float*)d_in[12];
  const float* bp2 = (const float*)d_in[13];
  const float* g_w = (const float*)d_in[14];
  const float* b_w = (const float*)d_in[15];
  const float* Ww1 = (const float*)d_in[16];
  const float* bw1 = (const float*)d_in[17];
  const float* Ww2 = (const float*)d_in[18];
  const float* bw2 = (const float*)d_in[19];

  char* ws = (char*)d_ws;
  float*    WqT  = (float*)(ws + 0);
  float*    WkT  = (float*)(ws + 16384);
  float*    WvT  = (float*)(ws + 32768);
  uint16_t* W1bf = (uint16_t*)(ws + 49152);
  uint16_t* W2bf = (uint16_t*)(ws + 57344);
  float*    a1w  = (float*)(ws + 65536);
  float*    hpaw = (float*)(ws + 66560);    // [1024][4]
  float*    qw   = (float*)(ws + 83968);    // [1024][64]
  float*    kw   = (float*)(ws + 347136);   // [1024][64]
  float*    vTw  = (float*)(ws + 610304);   // [2][64][512]
  float*    Rww  = (float*)(ws + 873472);   // [1024][4]
  float*    Cww  = (float*)(ws + 890880);   // [1024][4]
  float*    Mpw  = (float*)(ws + 907264);   // [16][8]
  float*    SNw  = (float*)(ws + 908288);   // [2][4][64]
  float*    a2w  = (float*)(ws + 911360);
  float*    be2w = (float*)(ws + 911616);
  float*    PtTw = (float*)(ws + 911872);   // [3][64]

  kpre<<<dim3(5), dim3(256), 0, stream>>>(Wq, Wk, Wv, Ww1, Ww2, pos, Wp1, g_p,
                                          WqT, WkT, WvT, W1bf, W2bf, a1w);
  k0<<<dim3(256), dim3(256), 0, stream>>>(cf, pos, WqT, WkT, WvT, bq, bk, bv,
                                          a1w, Wp1, bp2, qw, kw, vTw, hpaw);
  k1n<<<dim3(34), dim3(256), 0, stream>>>(hpaw, b_p, qw, kw, bp2, Rww, Cww, Mpw, SNw);
  k2n<<<dim3(1), dim3(1024), 0, stream>>>(qw, kw, bp2, Rww, Cww, Mpw, SNw,
                                          g_w, b_w, Wp2, a2w, be2w, PtTw);
  k3_main<<<dim3(1024), dim3(256), 0, stream>>>(qw, kw, vTw, hpaw, a2w, be2w, PtTw,
                                                W1bf, W2bf, bp2, Wp2, b_p, bw1, bw2,
                                                (float*)d_out);
}

// Round 4
// 133.933 us; speedup vs baseline: 1.7028x; 1.7028x over previous
//
#include <hip/hip_runtime.h>
#include <stdint.h>
#include <stddef.h>

#define DEV __device__ __forceinline__

typedef __attribute__((ext_vector_type(4))) float f32x4;
typedef __attribute__((ext_vector_type(8))) short bf16x8;

union FragU { bf16x8 f; uint32_t u[4]; };

DEV uint32_t pk_bf16(float a, float b) {
  uint32_t d;
  asm("v_cvt_pk_bf16_f32 %0, %1, %2" : "=v"(d) : "v"(a), "v"(b));
  return d;
}

DEV uint16_t f2bf(float x) {  // round-to-nearest-even
  uint32_t u = __float_as_uint(x);
  u += 0x7fffu + ((u >> 16) & 1u);
  return (uint16_t)(u >> 16);
}

// ---------------------------------------------------------------------------
// kP: bid<64: q/k/v GEMV (direct weight rows, L1-resident), 16 rows/block;
//     bid 64: Ww1/Ww2 -> bf16 frag order; bid 65: analytic BN1 -> a1,
//     counter reset.
// ---------------------------------------------------------------------------
__launch_bounds__(256)
__global__ void kP(const float* __restrict__ cf, const float* __restrict__ pos,
                   const float* __restrict__ Wq, const float* __restrict__ Wk,
                   const float* __restrict__ Wv, const float* __restrict__ bq,
                   const float* __restrict__ bk, const float* __restrict__ bv,
                   const float* __restrict__ Ww1, const float* __restrict__ Ww2,
                   const float* __restrict__ Wp1, const float* __restrict__ g_p,
                   const float* __restrict__ bp2,
                   float* __restrict__ qo, float* __restrict__ ko,
                   float* __restrict__ vT, uint16_t* __restrict__ W1bf,
                   uint16_t* __restrict__ W2bf, float* __restrict__ a1out,
                   unsigned int* __restrict__ counter) {
  const int bid = blockIdx.x, t = threadIdx.x;
  if (bid < 64) {
    const int rr = t >> 6, c = t & 63;
    const int r0 = bid * 16;
    const float* wqr = Wq + c * 64;
    const float* wkr = Wk + c * 64;
    const float* wvr = Wv + c * 64;
    const float biasq = bq[c], biask = bk[c], biasv = bv[c] + bp2[c];
    for (int chunk = 0; chunk < 4; ++chunk) {
      const int bn = r0 + chunk * 4 + rr;
      const float* cfr = cf + (size_t)bn * 64;
      float aq = biasq, ak = biask, av = biasv;
#pragma unroll 8
      for (int kk = 0; kk < 64; ++kk) {
        const float f = cfr[kk];
        aq = fmaf(f, wqr[kk], aq);
        ak = fmaf(f, wkr[kk], ak);
        av = fmaf(f, wvr[kk], av);
      }
      qo[(size_t)bn * 64 + c] = aq;
      ko[(size_t)bn * 64 + c] = ak;
      vT[((size_t)(bn >> 9) * 64 + c) * 512 + (bn & 511)] = av;
    }
  } else if (bid == 64) {
    // frag order: idx = ((nt*2+ks)*64 + lane)*8 + e
    for (int idx = t; idx < 8192; idx += 256) {
      const int m = idx >> 12;
      const int r = idx & 4095;
      const int f = r >> 9;
      const int l = (r >> 3) & 63;
      const int e = r & 7;
      const int nt = f >> 1, ks = f & 1, lm = l & 15, lq = l >> 4;
      const int row = 16 * nt + lm, col = 8 * lq + 32 * ks + e;
      const float src = m ? Ww2[row * 64 + col] : Ww1[row * 64 + col];
      (m ? W2bf : W1bf)[r] = f2bf(src);
    }
  } else {
    if (t == 0) counter[0] = 0u;
    __shared__ float acc9[2][9];
    __shared__ float red[256][10];
    __shared__ float red2[9][16];
    for (int b = 0; b < 2; ++b) {
      float s[9];
#pragma unroll
      for (int a = 0; a < 9; ++a) s[a] = 0.f;
      for (int r = 0; r < 2; ++r) {
        int i = t + 256 * r;
        const float* p = pos + (size_t)(b * 512 + i) * 3;
        float p0 = p[0], p1 = p[1], p2 = p[2];
        s[0] += p0; s[1] += p1; s[2] += p2;
        s[3] += p0 * p0; s[4] += p0 * p1; s[5] += p0 * p2;
        s[6] += p1 * p1; s[7] += p1 * p2; s[8] += p2 * p2;
      }
#pragma unroll
      for (int a = 0; a < 9; ++a) red[t][a] = s[a];
      __syncthreads();
      if (t < 144) {
        const int a = t >> 4, p = t & 15;
        float v = 0.f;
#pragma unroll
        for (int qq = 0; qq < 16; ++qq) v += red[p * 16 + qq][a];
        red2[a][p] = v;
      }
      __syncthreads();
      if (t < 9) {
        float v = 0.f;
#pragma unroll
        for (int p = 0; p < 16; ++p) v += red2[t][p];
        acc9[b][t] = v;
      }
      __syncthreads();
    }
    if (t == 0) {
      float C[6] = {0.f, 0.f, 0.f, 0.f, 0.f, 0.f};
      const float invM = 1.0f / 524288.0f;
      for (int b = 0; b < 2; ++b) {
        float S0 = acc9[b][0], S1 = acc9[b][1], S2 = acc9[b][2];
        float G00 = acc9[b][3], G01 = acc9[b][4], G02 = acc9[b][5];
        float G11 = acc9[b][6], G12 = acc9[b][7], G22 = acc9[b][8];
        C[0] += 1024.f * G00 - 2.f * S0 * S0;
        C[1] += 1024.f * G01 - 2.f * S0 * S1;
        C[2] += 1024.f * G02 - 2.f * S0 * S2;
        C[3] += 1024.f * G11 - 2.f * S1 * S1;
        C[4] += 1024.f * G12 - 2.f * S1 * S2;
        C[5] += 1024.f * G22 - 2.f * S2 * S2;
      }
      for (int a = 0; a < 6; ++a) C[a] *= invM;
      for (int tt = 0; tt < 3; ++tt) {
        float w0 = Wp1[tt * 3 + 0], w1 = Wp1[tt * 3 + 1], w2 = Wp1[tt * 3 + 2];
        float var = w0 * w0 * C[0] + w1 * w1 * C[3] + w2 * w2 * C[5]
                  + 2.f * (w0 * w1 * C[1] + w0 * w2 * C[2] + w1 * w2 * C[4]);
        a1out[tt] = g_p[tt] * rsqrtf(var + 1e-5f);
      }
      a1out[3] = 0.f;
    }
  }
}

// ---------------------------------------------------------------------------
// kB: bid<32: 3-ch pair pass (X staged in-block from pos; R/C sums + M
//     moments; chunk0/s0 blocks also write hpa); bid 32/33: per-batch
//     moments of u=q+bp2, k. Last block (device-scope atomic) assembles
//     BN2 -> a2, be2, PtT.
// ---------------------------------------------------------------------------
__launch_bounds__(256)
__global__ void kB(const float* __restrict__ pos, const float* __restrict__ a1,
                   const float* __restrict__ Wp1, const float* __restrict__ b_p,
                   const float* __restrict__ q, const float* __restrict__ k,
                   const float* __restrict__ bp2,
                   const float* __restrict__ g_w, const float* __restrict__ b_w,
                   const float* __restrict__ Wp2,
                   float* __restrict__ hpa, float* __restrict__ Rw,
                   float* __restrict__ Cw, float* __restrict__ Mpart,
                   float* __restrict__ SN, unsigned int* __restrict__ counter,
                   float* __restrict__ a2o, float* __restrict__ be2o,
                   float* __restrict__ PtT) {
  const int bid = blockIdx.x, t = threadIdx.x;
  __shared__ __align__(16) f32x4 X[512];
  __shared__ float redr[64][4][4];
  __shared__ float mred[256][6];
  __shared__ float mred2[64][6];
  __shared__ float redn[256][4];
  __shared__ float redc[256][6];
  __shared__ float shsc[4][3];
  __shared__ float Mf[6];
  __shared__ float Shf[3];
  __shared__ unsigned int isLast;

  if (bid < 32) {
    const int s = bid >> 4, b = (bid >> 3) & 1, chunk = bid & 7;
    const float a10 = a1[0], a11 = a1[1], a12 = a1[2];
    const float w00 = Wp1[0], w01 = Wp1[1], w02 = Wp1[2];
    const float w10 = Wp1[3], w11 = Wp1[4], w12 = Wp1[5];
    const float w20 = Wp1[6], w21 = Wp1[7], w22 = Wp1[8];
    for (int r = 0; r < 2; ++r) {
      const int row = t + 256 * r;
      const float* p = pos + (size_t)(b * 512 + row) * 3;
      const float p0 = p[0], p1 = p[1], p2 = p[2];
      f32x4 v;
      v.x = a10 * (w00 * p0 + w01 * p1 + w02 * p2);
      v.y = a11 * (w10 * p0 + w11 * p1 + w12 * p2);
      v.z = a12 * (w20 * p0 + w21 * p1 + w22 * p2);
      v.w = 0.f;
      if (s == 0 && chunk == 0)
        *(f32x4*)(hpa + (size_t)(b * 512 + row) * 4) = v;
      if (s) { v.x = -v.x; v.y = -v.y; v.z = -v.z; }
      X[row] = v;
    }
    __syncthreads();
    const int al = t >> 2, qr = t & 3;
    const int a = chunk * 64 + al;
    const f32x4 xa = X[a];
    const float base0 = xa.x + b_p[0], base1 = xa.y + b_p[1], base2 = xa.z + b_p[2];
    float r0 = 0, r1 = 0, r2 = 0;
    float m00 = 0, m01 = 0, m02 = 0, m11 = 0, m12 = 0, m22 = 0;
    for (int jj = qr * 128; jj < qr * 128 + 128; ++jj) {
      const f32x4 xj = X[jj];
      const float h0 = fmaxf(0.f, base0 - xj.x);
      const float h1 = fmaxf(0.f, base1 - xj.y);
      const float h2 = fmaxf(0.f, base2 - xj.z);
      r0 += h0; r1 += h1; r2 += h2;
      if (s == 0) {
        m00 = fmaf(h0, h0, m00); m01 = fmaf(h0, h1, m01); m02 = fmaf(h0, h2, m02);
        m11 = fmaf(h1, h1, m11); m12 = fmaf(h1, h2, m12); m22 = fmaf(h2, h2, m22);
      }
    }
    redr[al][qr][0] = r0; redr[al][qr][1] = r1; redr[al][qr][2] = r2; redr[al][qr][3] = 0.f;
    mred[t][0] = m00; mred[t][1] = m01; mred[t][2] = m02;
    mred[t][3] = m11; mred[t][4] = m12; mred[t][5] = m22;
    __syncthreads();
    if (t < 64) {
      float sx = 0, sy = 0, sz = 0;
#pragma unroll
      for (int p = 0; p < 4; ++p) { sx += redr[t][p][0]; sy += redr[t][p][1]; sz += redr[t][p][2]; }
      f32x4 dv; dv.x = sx; dv.y = sy; dv.z = sz; dv.w = 0.f;
      *(f32x4*)((s ? Cw : Rw) + (size_t)(b * 512 + chunk * 64 + t) * 4) = dv;
      if (s == 0) {
#pragma unroll
        for (int cc = 0; cc < 6; ++cc)
          mred2[t][cc] = mred[t][cc] + mred[t + 64][cc] + mred[t + 128][cc] + mred[t + 192][cc];
      }
    }
    __syncthreads();
    if (s == 0 && t < 6) {
      float m = 0.f;
      for (int p = 0; p < 64; ++p) m += mred2[p][t];
      Mpart[bid * 8 + t] = m;
    }
  } else {
    const int b = bid - 32;
    const int c = t & 63, g = t >> 6;
    float su = 0, su2 = 0, sk = 0, sk2 = 0;
    const float bp = bp2[c];
    for (int i = g * 128; i < g * 128 + 128; ++i) {
      const float uq = q[(size_t)(b * 512 + i) * 64 + c] + bp;
      const float kv = k[(size_t)(b * 512 + i) * 64 + c];
      su += uq; su2 = fmaf(uq, uq, su2);
      sk += kv; sk2 = fmaf(kv, kv, sk2);
    }
    redn[t][0] = su; redn[t][1] = su2; redn[t][2] = sk; redn[t][3] = sk2;
    __syncthreads();
    if (t < 64) {
      float a0 = 0, a1v = 0, a2v = 0, a3 = 0;
#pragma unroll
      for (int p = 0; p < 4; ++p) {
        a0 += redn[t + 64 * p][0]; a1v += redn[t + 64 * p][1];
        a2v += redn[t + 64 * p][2]; a3 += redn[t + 64 * p][3];
      }
      SN[(b * 4 + 0) * 64 + t] = a0;
      SN[(b * 4 + 1) * 64 + t] = a1v;
      SN[(b * 4 + 2) * 64 + t] = a2v;
      SN[(b * 4 + 3) * 64 + t] = a3;
    }
  }

  // ---- completion: last block assembles BN2 stats ----
  __syncthreads();
  if (t == 0) {
    __threadfence();
    const unsigned int old = atomicAdd(counter, 1u);
    isLast = (old == 33u) ? 1u : 0u;
  }
  __syncthreads();
  if (isLast) {
    __threadfence();
    const int c = t & 63, g = t >> 6;  // g: 0..3
    float urd0 = 0, urd1 = 0, urd2 = 0;
    float shp0 = 0, shp1 = 0, shp2 = 0;
    const float bp = bp2[c];
    for (int it2 = 0; it2 < 256; ++it2) {
      const size_t row = (size_t)(g * 256 + it2);
      const float uq = q[row * 64 + c] + bp;
      const float kv = k[row * 64 + c];
      const f32x4 rv = *(const f32x4*)(Rw + row * 4);
      const f32x4 cv = *(const f32x4*)(Cw + row * 4);
      urd0 += uq * rv.x - kv * cv.x;
      urd1 += uq * rv.y - kv * cv.y;
      urd2 += uq * rv.z - kv * cv.z;
      if (c == 0) { shp0 += rv.x; shp1 += rv.y; shp2 += rv.z; }
    }
    redc[t][0] = urd0; redc[t][1] = urd1; redc[t][2] = urd2;
    if (c == 0) { shsc[g][0] = shp0; shsc[g][1] = shp1; shsc[g][2] = shp2; }
    __syncthreads();
    if (t < 6) {
      float m = 0.f;
      for (int p = 0; p < 16; ++p) m += Mpart[p * 8 + t];
      Mf[t] = m;
    }
    if (t >= 64 && t < 67) {
      const int tt = t - 64;
      Shf[tt] = shsc[0][tt] + shsc[1][tt] + shsc[2][tt] + shsc[3][tt];
    }
    __syncthreads();
    if (t < 64) {
      float URd0 = 0, URd1 = 0, URd2 = 0;
#pragma unroll
      for (int p = 0; p < 4; ++p) {
        URd0 += redc[t + 64 * p][0];
        URd1 += redc[t + 64 * p][1];
        URd2 += redc[t + 64 * p][2];
      }
      const float P0t = Wp2[t * 3 + 0], P1t = Wp2[t * 3 + 1], P2t = Wp2[t * 3 + 2];
      const float Nf = 512.f, invM = 1.f / 524288.f;
      float S1 = 0.f, Q2 = 0.f;
#pragma unroll
      for (int b = 0; b < 2; ++b) {
        const float Su = SN[(b * 4 + 0) * 64 + t];
        const float Su2 = SN[(b * 4 + 1) * 64 + t];
        const float Sk = SN[(b * 4 + 2) * 64 + t];
        const float Sk2 = SN[(b * 4 + 3) * 64 + t];
        S1 += Nf * (Su - Sk);
        Q2 += Nf * Su2 - 2.f * Su * Sk + Nf * Sk2;
      }
      const float Xc = P0t * URd0 + P1t * URd1 + P2t * URd2;
      S1 += P0t * Shf[0] + P1t * Shf[1] + P2t * Shf[2];
      const float Hm = P0t * P0t * Mf[0] + 2.f * P0t * P1t * Mf[1] + 2.f * P0t * P2t * Mf[2]
                     + P1t * P1t * Mf[3] + 2.f * P1t * P2t * Mf[4] + P2t * P2t * Mf[5];
      const float E1 = S1 * invM;
      const float E2 = (Q2 + 2.f * Xc + Hm) * invM;
      const float var = E2 - E1 * E1;
      const float rstd = rsqrtf(var + 1e-5f);
      const float A2 = g_w[t] * rstd;
      a2o[t] = A2;
      be2o[t] = b_w[t] - E1 * A2;
      PtT[0 * 64 + t] = A2 * P0t;
      PtT[1 * 64 + t] = A2 * P1t;
      PtT[2 * 64 + t] = A2 * P2t;
    }
  }
}

// ---------------------------------------------------------------------------
// k3: fused main. Round-2 skeleton (LDS stage-A consts, plain loop) +
// frag-linear weight LDS + no-max softmax + bp2-folded v + H2 pad 76.
// ---------------------------------------------------------------------------
__launch_bounds__(256)
__global__ void k3_main(const float* __restrict__ q, const float* __restrict__ kk_,
                        const float* __restrict__ vT, const float* __restrict__ hpa,
                        const float* __restrict__ a2g, const float* __restrict__ be2g,
                        const float* __restrict__ PtTg,
                        const uint16_t* __restrict__ W1bf, const uint16_t* __restrict__ W2bf,
                        const float* __restrict__ bp2, const float* __restrict__ Wp2,
                        const float* __restrict__ b_p, const float* __restrict__ bw1g,
                        const float* __restrict__ bw2g, float* __restrict__ out) {
  const int bid = blockIdx.x;
  const int b = bid >> 9, i = bid & 511;
  const int t = threadIdx.x;
  const int wid = t >> 6, l = t & 63;
  const int lm = l & 15, lq = l >> 4;

  __shared__ __align__(16) uint16_t W1l[4096];
  __shared__ __align__(16) uint16_t W2l[4096];
  __shared__ __align__(16) uint16_t H2[4][16][76];
  __shared__ __align__(16) float P0[64];
  __shared__ __align__(16) float a2s[64];
  __shared__ __align__(16) float Pts[3][64];
  __shared__ __align__(16) float comb[4][64][2];

  // stage weights (frag-linear, conflict-free uniform b128)
  {
    *(bf16x8*)(&W1l[t * 16])     = *(const bf16x8*)(W1bf + t * 16);
    *(bf16x8*)(&W1l[t * 16 + 8]) = *(const bf16x8*)(W1bf + t * 16 + 8);
    *(bf16x8*)(&W2l[t * 16])     = *(const bf16x8*)(W2bf + t * 16);
    *(bf16x8*)(&W2l[t * 16 + 8]) = *(const bf16x8*)(W2bf + t * 16 + 8);
  }
  if (t < 64) {
    const float a2v = a2g[t];
    a2s[t] = a2v;
    P0[t] = fmaf(a2v, q[(size_t)(b * 512 + i) * 64 + t] + bp2[t], be2g[t]);
  } else {
    const int idx = t - 64;
    Pts[idx >> 6][idx & 63] = PtTg[idx];
  }

  const f32x4 hi = *(const f32x4*)(hpa + (size_t)(b * 512 + i) * 4);
  const float bb0 = b_p[0], bb1 = b_p[1], bb2 = b_p[2];
  const float LOG2E = 1.4426950408889634f;

  float bw1r[4], bw2l[4], wpa[4], wpb[4], wpc[4];
#pragma unroll
  for (int nt = 0; nt < 4; ++nt) {
    const int c = 16 * nt + lm;
    bw1r[nt] = bw1g[c];
    bw2l[nt] = bw2g[c] * LOG2E;
    wpa[nt] = Wp2[c * 3 + 0];
    wpb[nt] = Wp2[c * 3 + 1];
    wpc[nt] = Wp2[c * 3 + 2];
  }

  float l_[4] = {0.f, 0.f, 0.f, 0.f};
  float acc_[4] = {0.f, 0.f, 0.f, 0.f};

  __syncthreads();

  const float* kbase = kk_ + (size_t)(b * 512) * 64;
  const float* hbase = hpa + (size_t)(b * 512) * 4;
  const float* vTb = vT + (size_t)b * 64 * 512;

  for (int it = 0; it < 8; ++it) {
    const int jb = it * 64 + wid * 16;
    const int j = jb + lm;
    const int j2 = jb + 4 * lq;

    // per-iter loads (issued up front; L2-hot)
    f32x4 kv[2][2];
#pragma unroll
    for (int ks = 0; ks < 2; ++ks) {
      kv[ks][0] = *(const f32x4*)(kbase + (size_t)j * 64 + 32 * ks + 8 * lq);
      kv[ks][1] = *(const f32x4*)(kbase + (size_t)j * 64 + 32 * ks + 8 * lq + 4);
    }
    const f32x4 hj = *(const f32x4*)(hbase + j * 4);
    f32x4 hjr[4];
#pragma unroll
    for (int r = 0; r < 4; ++r) hjr[r] = *(const f32x4*)(hbase + (j2 + r) * 4);
    f32x4 vv[4];
#pragma unroll
    for (int nt = 0; nt < 4; ++nt)
      vv[nt] = *(const f32x4*)(vTb + (size_t)(16 * nt + lm) * 512 + j2);

    // ---- stage A: x = relu(a2*qk + b2) as A-fragments ----
    const float h0 = fmaxf(0.f, hi.x - hj.x + bb0);
    const float h1 = fmaxf(0.f, hi.y - hj.y + bb1);
    const float h2v = fmaxf(0.f, hi.z - hj.z + bb2);

    FragU A1[2];
#pragma unroll
    for (int ks = 0; ks < 2; ++ks) {
      const int c0 = 32 * ks + 8 * lq;
      f32x4 pv[2], av[2], t0[2], t1[2], t2[2];
      pv[0] = *(const f32x4*)(P0 + c0);        pv[1] = *(const f32x4*)(P0 + c0 + 4);
      av[0] = *(const f32x4*)(a2s + c0);       av[1] = *(const f32x4*)(a2s + c0 + 4);
      t0[0] = *(const f32x4*)(&Pts[0][c0]);    t0[1] = *(const f32x4*)(&Pts[0][c0 + 4]);
      t1[0] = *(const f32x4*)(&Pts[1][c0]);    t1[1] = *(const f32x4*)(&Pts[1][c0 + 4]);
      t2[0] = *(const f32x4*)(&Pts[2][c0]);    t2[1] = *(const f32x4*)(&Pts[2][c0 + 4]);
      float x[8];
#pragma unroll
      for (int e = 0; e < 8; ++e) {
        const int hh = e >> 2, e4 = e & 3;
        float xv = pv[hh][e4] - av[hh][e4] * kv[ks][hh][e4];
        xv = fmaf(t0[hh][e4], h0, xv);
        xv = fmaf(t1[hh][e4], h1, xv);
        xv = fmaf(t2[hh][e4], h2v, xv);
        x[e] = fmaxf(0.f, xv);
      }
      A1[ks].u[0] = pk_bf16(x[0], x[1]);
      A1[ks].u[1] = pk_bf16(x[2], x[3]);
      A1[ks].u[2] = pk_bf16(x[4], x[5]);
      A1[ks].u[3] = pk_bf16(x[6], x[7]);
    }

    // ---- GEMM1 ----
    f32x4 d1[4];
#pragma unroll
    for (int nt = 0; nt < 4; ++nt) {
      FragU b0, b1;
      b0.f = *(const bf16x8*)(&W1l[((nt * 2 + 0) * 64 + l) * 8]);
      b1.f = *(const bf16x8*)(&W1l[((nt * 2 + 1) * 64 + l) * 8]);
      f32x4 z = {0.f, 0.f, 0.f, 0.f};
      z = __builtin_amdgcn_mfma_f32_16x16x32_bf16(A1[0].f, b0.f, z, 0, 0, 0);
      z = __builtin_amdgcn_mfma_f32_16x16x32_bf16(A1[1].f, b1.f, z, 0, 0, 0);
      d1[nt] = z;
    }

    // ---- bias+relu, repack h2 to bf16 LDS (per-wave private, pad 76) ----
    uint16_t (*h2w)[76] = H2[wid];
#pragma unroll
    for (int nt = 0; nt < 4; ++nt) {
      const float e0 = fmaxf(0.f, d1[nt][0] + bw1r[nt]);
      const float e1 = fmaxf(0.f, d1[nt][1] + bw1r[nt]);
      const float e2 = fmaxf(0.f, d1[nt][2] + bw1r[nt]);
      const float e3 = fmaxf(0.f, d1[nt][3] + bw1r[nt]);
      const uint32_t u01 = pk_bf16(e0, e1);
      const uint32_t u23 = pk_bf16(e2, e3);
      const int col = 16 * nt + lm;
      h2w[4 * lq + 0][col] = (uint16_t)(u01 & 0xffffu);
      h2w[4 * lq + 1][col] = (uint16_t)(u01 >> 16);
      h2w[4 * lq + 2][col] = (uint16_t)(u23 & 0xffffu);
      h2w[4 * lq + 3][col] = (uint16_t)(u23 >> 16);
    }

    FragU A2[2];
    A2[0].f = *(const bf16x8*)(&h2w[lm][8 * lq]);
    A2[1].f = *(const bf16x8*)(&h2w[lm][32 + 8 * lq]);

    // ---- GEMM2 ----
    f32x4 d2[4];
#pragma unroll
    for (int nt = 0; nt < 4; ++nt) {
      FragU b0, b1;
      b0.f = *(const bf16x8*)(&W2l[((nt * 2 + 0) * 64 + l) * 8]);
      b1.f = *(const bf16x8*)(&W2l[((nt * 2 + 1) * 64 + l) * 8]);
      f32x4 z = {0.f, 0.f, 0.f, 0.f};
      z = __builtin_amdgcn_mfma_f32_16x16x32_bf16(A2[0].f, b0.f, z, 0, 0, 0);
      z = __builtin_amdgcn_mfma_f32_16x16x32_bf16(A2[1].f, b1.f, z, 0, 0, 0);
      d2[nt] = z;
    }

    // ---- hr for this lane's 4 output j-rows ----
    float hr0[4], hr1[4], hr2[4];
#pragma unroll
    for (int r = 0; r < 4; ++r) {
      hr0[r] = fmaxf(0.f, hi.x - hjr[r].x + bb0);
      hr1[r] = fmaxf(0.f, hi.y - hjr[r].y + bb1);
      hr2[r] = fmaxf(0.f, hi.z - hjr[r].z + bb2);
    }

    // ---- no-max softmax accumulation ----
#pragma unroll
    for (int nt = 0; nt < 4; ++nt) {
      float p[4], val[4];
#pragma unroll
      for (int r = 0; r < 4; ++r) {
        p[r] = __builtin_amdgcn_exp2f(fmaf(d2[nt][r], LOG2E, bw2l[nt]));
        float v0 = vv[nt][r];
        v0 = fmaf(wpa[nt], hr0[r], v0);
        v0 = fmaf(wpb[nt], hr1[r], v0);
        v0 = fmaf(wpc[nt], hr2[r], v0);
        val[r] = v0;
      }
      l_[nt] += (p[0] + p[1]) + (p[2] + p[3]);
      float a = acc_[nt];
      a = fmaf(p[0], val[0], a);
      a = fmaf(p[1], val[1], a);
      a = fmaf(p[2], val[2], a);
      a = fmaf(p[3], val[3], a);
      acc_[nt] = a;
    }
  }

  // ---- combine (linear): shfl over lq groups, then across waves ----
#pragma unroll
  for (int nt = 0; nt < 4; ++nt) {
    l_[nt] += __shfl_xor(l_[nt], 16);
    acc_[nt] += __shfl_xor(acc_[nt], 16);
    l_[nt] += __shfl_xor(l_[nt], 32);
    acc_[nt] += __shfl_xor(acc_[nt], 32);
  }
  if (lq == 0) {
#pragma unroll
    for (int nt = 0; nt < 4; ++nt) {
      comb[wid][16 * nt + lm][0] = l_[nt];
      comb[wid][16 * nt + lm][1] = acc_[nt];
    }
  }
  __syncthreads();
  if (t < 64) {
    float L = 0.f, A = 0.f;
#pragma unroll
    for (int w = 0; w < 4; ++w) {
      L += comb[w][t][0];
      A += comb[w][t][1];
    }
    out[(size_t)(b * 512 + i) * 64 + t] = A / L;
  }
}

// ---------------------------------------------------------------------------
extern "C" void kernel_launch(void* const* d_in, const int* in_sizes, int n_in,
                              void* d_out, int out_size, void* d_ws, size_t ws_size,
                              hipStream_t stream) {
  (void)in_sizes; (void)n_in; (void)out_size; (void)ws_size;
  const float* pos = (const float*)d_in[0];
  const float* cf  = (const float*)d_in[1];
  const float* Wq  = (const float*)d_in[2];
  const float* bq  = (const float*)d_in[3];
  const float* Wk  = (const float*)d_in[4];
  const float* bk  = (const float*)d_in[5];
  const float* Wv  = (const float*)d_in[6];
  const float* bv  = (const float*)d_in[7];
  const float* Wp1 = (const float*)d_in[8];
  // d_in[9] = bp1: cancels analytically (gamma1 == b_p exactly)
  const float* g_p = (const float*)d_in[10];
  const float* b_p = (const float*)d_in[11];
  const float* Wp2 = (const float*)d_in[12];
  const float* bp2 = (const float*)d_in[13];
  const float* g_w = (const float*)d_in[14];
  const float* b_w = (const float*)d_in[15];
  const float* Ww1 = (const float*)d_in[16];
  const float* bw1 = (const float*)d_in[17];
  const float* Ww2 = (const float*)d_in[18];
  const float* bw2 = (const float*)d_in[19];

  char* ws = (char*)d_ws;
  uint16_t*     W1bf = (uint16_t*)(ws + 0);        // 8192 B
  uint16_t*     W2bf = (uint16_t*)(ws + 8192);     // 8192 B
  float*        a1w  = (float*)(ws + 16384);       // 16 B
  unsigned int* cnt  = (unsigned int*)(ws + 16640);
  float*        hpaw = (float*)(ws + 16896);       // [1024][4]
  float*        qw   = (float*)(ws + 33280);       // [1024][64]
  float*        kw   = (float*)(ws + 295424);      // [1024][64]
  float*        vTw  = (float*)(ws + 557568);      // [2][64][512]
  float*        Rww  = (float*)(ws + 819712);      // [1024][4]
  float*        Cww  = (float*)(ws + 836096);      // [1024][4]
  float*        Mpw  = (float*)(ws + 852480);      // [16][8]
  float*        SNw  = (float*)(ws + 852992);      // [2][4][64]
  float*        a2w  = (float*)(ws + 855040);
  float*        be2w = (float*)(ws + 855296);
  float*        PtTw = (float*)(ws + 855552);      // [3][64]

  kP<<<dim3(66), dim3(256), 0, stream>>>(cf, pos, Wq, Wk, Wv, bq, bk, bv,
                                         Ww1, Ww2, Wp1, g_p, bp2,
                                         qw, kw, vTw, W1bf, W2bf, a1w, cnt);
  kB<<<dim3(34), dim3(256), 0, stream>>>(pos, a1w, Wp1, b_p, qw, kw, bp2,
                                         g_w, b_w, Wp2,
                                         hpaw, Rww, Cww, Mpw, SNw, cnt,
                                         a2w, be2w, PtTw);
  k3_main<<<dim3(1024), dim3(256), 0, stream>>>(qw, kw, vTw, hpaw, a2w, be2w, PtTw,
                                                W1bf, W2bf, bp2, Wp2, b_p, bw1, bw2,
                                                (float*)d_out);
}

// Round 5
// 72.425 us; speedup vs baseline: 3.1489x; 1.8493x over previous
//
#include <hip/hip_runtime.h>
#include <stdint.h>
#include <stddef.h>

#define DEV __device__ __forceinline__

typedef __attribute__((ext_vector_type(4))) float f32x4;
typedef __attribute__((ext_vector_type(8))) short bf16x8;

union FragU { bf16x8 f; uint32_t u[4]; };

DEV uint32_t pk_bf16(float a, float b) {
  uint32_t d;
  asm("v_cvt_pk_bf16_f32 %0, %1, %2" : "=v"(d) : "v"(a), "v"(b));
  return d;
}

DEV uint16_t f2bf(float x) {  // round-to-nearest-even
  uint32_t u = __float_as_uint(x);
  u += 0x7fffu + ((u >> 16) & 1u);
  return (uint16_t)(u >> 16);
}

// ---------------------------------------------------------------------------
// kP: bid<256: q/k/v GEMV (4 rows/block, direct weight rows);
//     bid 256: Ww1/Ww2 -> bf16 frag order; bid 257: analytic BN1 -> a1 +
//     counter reset.
// ---------------------------------------------------------------------------
__launch_bounds__(256)
__global__ void kP(const float* __restrict__ cf, const float* __restrict__ pos,
                   const float* __restrict__ Wq, const float* __restrict__ Wk,
                   const float* __restrict__ Wv, const float* __restrict__ bq,
                   const float* __restrict__ bk, const float* __restrict__ bv,
                   const float* __restrict__ Ww1, const float* __restrict__ Ww2,
                   const float* __restrict__ Wp1, const float* __restrict__ g_p,
                   const float* __restrict__ bp2,
                   float* __restrict__ qo, float* __restrict__ ko,
                   float* __restrict__ vT, uint16_t* __restrict__ W1bf,
                   uint16_t* __restrict__ W2bf, float* __restrict__ a1out,
                   unsigned int* __restrict__ counter) {
  const int bid = blockIdx.x, t = threadIdx.x;
  if (bid < 256) {
    __shared__ float cfl[4][64];
    const int rr = t >> 6, c = t & 63;
    const int r0 = bid * 4;
    cfl[rr][c] = cf[(size_t)(r0 + rr) * 64 + c];
    __syncthreads();
    const int bn = r0 + rr;
    const float* wqr = Wq + c * 64;
    const float* wkr = Wk + c * 64;
    const float* wvr = Wv + c * 64;
    float aq = bq[c], ak = bk[c], av = bv[c] + bp2[c];
#pragma unroll 8
    for (int kk = 0; kk < 64; ++kk) {
      const float f = cfl[rr][kk];
      aq = fmaf(f, wqr[kk], aq);
      ak = fmaf(f, wkr[kk], ak);
      av = fmaf(f, wvr[kk], av);
    }
    qo[(size_t)bn * 64 + c] = aq;
    ko[(size_t)bn * 64 + c] = ak;
    vT[((size_t)(bn >> 9) * 64 + c) * 512 + (bn & 511)] = av;
  } else if (bid == 256) {
    // frag order: idx = ((nt*2+ks)*64 + lane)*8 + e
    for (int idx = t; idx < 8192; idx += 256) {
      const int m = idx >> 12;
      const int r = idx & 4095;
      const int f = r >> 9;
      const int l = (r >> 3) & 63;
      const int e = r & 7;
      const int nt = f >> 1, ks = f & 1, lm = l & 15, lq = l >> 4;
      const int row = 16 * nt + lm, col = 8 * lq + 32 * ks + e;
      const float src = m ? Ww2[row * 64 + col] : Ww1[row * 64 + col];
      (m ? W2bf : W1bf)[r] = f2bf(src);
    }
  } else {
    if (t == 0) counter[0] = 0u;
    __shared__ float acc9[2][9];
    __shared__ float red[256][10];
    __shared__ float red2[9][16];
    for (int b = 0; b < 2; ++b) {
      float s[9];
#pragma unroll
      for (int a = 0; a < 9; ++a) s[a] = 0.f;
      for (int r = 0; r < 2; ++r) {
        int i = t + 256 * r;
        const float* p = pos + (size_t)(b * 512 + i) * 3;
        float p0 = p[0], p1 = p[1], p2 = p[2];
        s[0] += p0; s[1] += p1; s[2] += p2;
        s[3] += p0 * p0; s[4] += p0 * p1; s[5] += p0 * p2;
        s[6] += p1 * p1; s[7] += p1 * p2; s[8] += p2 * p2;
      }
#pragma unroll
      for (int a = 0; a < 9; ++a) red[t][a] = s[a];
      __syncthreads();
      if (t < 144) {
        const int a = t >> 4, p = t & 15;
        float v = 0.f;
#pragma unroll
        for (int qq = 0; qq < 16; ++qq) v += red[p * 16 + qq][a];
        red2[a][p] = v;
      }
      __syncthreads();
      if (t < 9) {
        float v = 0.f;
#pragma unroll
        for (int p = 0; p < 16; ++p) v += red2[t][p];
        acc9[b][t] = v;
      }
      __syncthreads();
    }
    if (t == 0) {
      float C[6] = {0.f, 0.f, 0.f, 0.f, 0.f, 0.f};
      const float invM = 1.0f / 524288.0f;
      for (int b = 0; b < 2; ++b) {
        float S0 = acc9[b][0], S1 = acc9[b][1], S2 = acc9[b][2];
        float G00 = acc9[b][3], G01 = acc9[b][4], G02 = acc9[b][5];
        float G11 = acc9[b][6], G12 = acc9[b][7], G22 = acc9[b][8];
        C[0] += 1024.f * G00 - 2.f * S0 * S0;
        C[1] += 1024.f * G01 - 2.f * S0 * S1;
        C[2] += 1024.f * G02 - 2.f * S0 * S2;
        C[3] += 1024.f * G11 - 2.f * S1 * S1;
        C[4] += 1024.f * G12 - 2.f * S1 * S2;
        C[5] += 1024.f * G22 - 2.f * S2 * S2;
      }
      for (int a = 0; a < 6; ++a) C[a] *= invM;
      for (int tt = 0; tt < 3; ++tt) {
        float w0 = Wp1[tt * 3 + 0], w1 = Wp1[tt * 3 + 1], w2 = Wp1[tt * 3 + 2];
        float var = w0 * w0 * C[0] + w1 * w1 * C[3] + w2 * w2 * C[5]
                  + 2.f * (w0 * w1 * C[1] + w0 * w2 * C[2] + w1 * w2 * C[4]);
        a1out[tt] = g_p[tt] * rsqrtf(var + 1e-5f);
      }
      a1out[3] = 0.f;
    }
  }
}

// ---------------------------------------------------------------------------
// kB: 32 blocks (s,b,chunk). Each block computes COMPLETE R_t (s=0) or C_t
// (s=1) for its 64 rows, then folds all downstream sums into small partials:
//   XPp  = +-sum_rows U[row][c]*r_t(row)   (pre-signed cross term)
//   SNp  = per-channel sum / sumsq of U    (u for s=0, k for s=1)
//   Mpart= M moments + Sh (s=0 only)
// Last block (atomic) assembles a2, be2, PtT from partials only (~micro work).
// ---------------------------------------------------------------------------
__launch_bounds__(256)
__global__ void kB(const float* __restrict__ pos, const float* __restrict__ a1,
                   const float* __restrict__ Wp1, const float* __restrict__ b_p,
                   const float* __restrict__ q, const float* __restrict__ k,
                   const float* __restrict__ bp2,
                   const float* __restrict__ g_w, const float* __restrict__ b_w,
                   const float* __restrict__ Wp2,
                   float* __restrict__ hpa, float* __restrict__ Mpart,
                   float* __restrict__ XPp, float* __restrict__ SNp,
                   unsigned int* __restrict__ counter,
                   float* __restrict__ a2o, float* __restrict__ be2o,
                   float* __restrict__ PtT) {
  const int bid = blockIdx.x, t = threadIdx.x;
  const int s = bid >> 4, b = (bid >> 3) & 1, chunk = bid & 7;

  __shared__ __align__(16) f32x4 X[512];     // hpa (negated for s=1)
  __shared__ float U[64][64];                // own 64 rows of u or k
  __shared__ float redr[64][4][4];
  __shared__ float mred[256][6];
  __shared__ float mred2[64][6];
  __shared__ float rfin[64][4];
  __shared__ float redn[256][2];
  __shared__ float MfS[6];
  __shared__ float ShfS[3];
  __shared__ unsigned int isLast;

  // ---- stage X (compute hpa from pos); blocks (s=0,chunk=0) write hpa ----
  {
    const float a10 = a1[0], a11 = a1[1], a12 = a1[2];
    const float w00 = Wp1[0], w01 = Wp1[1], w02 = Wp1[2];
    const float w10 = Wp1[3], w11 = Wp1[4], w12 = Wp1[5];
    const float w20 = Wp1[6], w21 = Wp1[7], w22 = Wp1[8];
    for (int r = 0; r < 2; ++r) {
      const int row = t + 256 * r;
      const float* p = pos + (size_t)(b * 512 + row) * 3;
      const float p0 = p[0], p1 = p[1], p2 = p[2];
      f32x4 v;
      v.x = a10 * (w00 * p0 + w01 * p1 + w02 * p2);
      v.y = a11 * (w10 * p0 + w11 * p1 + w12 * p2);
      v.z = a12 * (w20 * p0 + w21 * p1 + w22 * p2);
      v.w = 0.f;
      if (s == 0 && chunk == 0)
        *(f32x4*)(hpa + (size_t)(b * 512 + row) * 4) = v;
      if (s) { v.x = -v.x; v.y = -v.y; v.z = -v.z; }
      X[row] = v;
    }
  }
  // ---- stage U: own 64 rows of (s ? k : q+bp2) ----
  {
    const float* src = s ? k : q;
    const int r0g = b * 512 + chunk * 64;
#pragma unroll
    for (int e = 0; e < 16; ++e) {
      const int idx = e * 256 + t;
      const int row = idx >> 6, c = idx & 63;
      float v = src[(size_t)(r0g + row) * 64 + c];
      if (!s) v += bp2[c];
      U[row][c] = v;
    }
  }
  __syncthreads();

  // ---- pair loop: complete R/C for this block's 64 rows ----
  {
    const int al = t >> 2, qr = t & 3;
    const int a = chunk * 64 + al;
    const f32x4 xa = X[a];
    const float base0 = xa.x + b_p[0], base1 = xa.y + b_p[1], base2 = xa.z + b_p[2];
    float r0 = 0, r1 = 0, r2 = 0;
    float m00 = 0, m01 = 0, m02 = 0, m11 = 0, m12 = 0, m22 = 0;
#pragma unroll 8
    for (int jj = qr * 128; jj < qr * 128 + 128; ++jj) {
      const f32x4 xj = X[jj];
      const float h0 = fmaxf(0.f, base0 - xj.x);
      const float h1 = fmaxf(0.f, base1 - xj.y);
      const float h2 = fmaxf(0.f, base2 - xj.z);
      r0 += h0; r1 += h1; r2 += h2;
      if (s == 0) {
        m00 = fmaf(h0, h0, m00); m01 = fmaf(h0, h1, m01); m02 = fmaf(h0, h2, m02);
        m11 = fmaf(h1, h1, m11); m12 = fmaf(h1, h2, m12); m22 = fmaf(h2, h2, m22);
      }
    }
    redr[al][qr][0] = r0; redr[al][qr][1] = r1; redr[al][qr][2] = r2; redr[al][qr][3] = 0.f;
    mred[t][0] = m00; mred[t][1] = m01; mred[t][2] = m02;
    mred[t][3] = m11; mred[t][4] = m12; mred[t][5] = m22;
  }
  __syncthreads();

  if (t < 64) {
    float sx = 0, sy = 0, sz = 0;
#pragma unroll
    for (int p = 0; p < 4; ++p) { sx += redr[t][p][0]; sy += redr[t][p][1]; sz += redr[t][p][2]; }
    rfin[t][0] = sx; rfin[t][1] = sy; rfin[t][2] = sz; rfin[t][3] = 0.f;
    if (s == 0) {
#pragma unroll
      for (int cc = 0; cc < 6; ++cc)
        mred2[t][cc] = mred[t][cc] + mred[t + 64][cc] + mred[t + 128][cc] + mred[t + 192][cc];
    }
  }
  __syncthreads();

  // ---- fold partials ----
  if (s == 0 && t < 6) {
    float m = 0.f;
    for (int p = 0; p < 64; ++p) m += mred2[p][t];
    Mpart[bid * 12 + t] = m;
  }
  if (s == 0 && t >= 64 && t < 67) {
    const int tt = t - 64;
    float v = 0.f;
#pragma unroll 8
    for (int a = 0; a < 64; ++a) v += rfin[a][tt];
    Mpart[bid * 12 + 6 + tt] = v;
  }
  if (t < 192) {
    const int c = t & 63, tt = t >> 6;
    float xp = 0.f;
#pragma unroll 8
    for (int a = 0; a < 64; ++a) xp = fmaf(U[a][c], rfin[a][tt], xp);
    if (s) xp = -xp;
    XPp[((size_t)bid * 3 + tt) * 64 + c] = xp;
  }
  {
    const int c = t & 63, g = t >> 6;
    float su = 0.f, su2 = 0.f;
#pragma unroll
    for (int r = 0; r < 16; ++r) {
      const float v = U[g * 16 + r][c];
      su += v;
      su2 = fmaf(v, v, su2);
    }
    redn[t][0] = su; redn[t][1] = su2;
  }
  __syncthreads();
  if (t < 64) {
    float a0 = 0.f, a1v = 0.f;
#pragma unroll
    for (int p = 0; p < 4; ++p) { a0 += redn[t + 64 * p][0]; a1v += redn[t + 64 * p][1]; }
    SNp[((size_t)bid * 2 + 0) * 64 + t] = a0;
    SNp[((size_t)bid * 2 + 1) * 64 + t] = a1v;
  }

  // ---- completion: last block assembles from partials only ----
  __syncthreads();
  if (t == 0) {
    __threadfence();
    const unsigned int old = atomicAdd(counter, 1u);
    isLast = (old == 31u) ? 1u : 0u;
  }
  __syncthreads();
  if (isLast) {
    __threadfence();
    if (t < 6) {
      float m = 0.f;
#pragma unroll
      for (int p = 0; p < 16; ++p) m += Mpart[p * 12 + t];
      MfS[t] = m;
    }
    if (t >= 6 && t < 9) {
      const int tt = t - 6;
      float v = 0.f;
#pragma unroll
      for (int p = 0; p < 16; ++p) v += Mpart[p * 12 + 6 + tt];
      ShfS[tt] = v;
    }
    __syncthreads();
    if (t < 64) {
      const int c = t;
      // per-batch sums of u and k
      float Su[2], Su2[2], Sk[2], Sk2[2];
#pragma unroll
      for (int bb = 0; bb < 2; ++bb) {
        float a0 = 0.f, a1v = 0.f, a2v = 0.f, a3 = 0.f;
#pragma unroll
        for (int p = 0; p < 8; ++p) {
          const int blkU = bb * 8 + p;        // s=0
          const int blkK = 16 + bb * 8 + p;   // s=1
          a0 += SNp[((size_t)blkU * 2 + 0) * 64 + c];
          a1v += SNp[((size_t)blkU * 2 + 1) * 64 + c];
          a2v += SNp[((size_t)blkK * 2 + 0) * 64 + c];
          a3 += SNp[((size_t)blkK * 2 + 1) * 64 + c];
        }
        Su[bb] = a0; Su2[bb] = a1v; Sk[bb] = a2v; Sk2[bb] = a3;
      }
      // cross-term sums (pre-signed)
      float URd0 = 0.f, URd1 = 0.f, URd2 = 0.f;
#pragma unroll
      for (int blk = 0; blk < 32; ++blk) {
        URd0 += XPp[((size_t)blk * 3 + 0) * 64 + c];
        URd1 += XPp[((size_t)blk * 3 + 1) * 64 + c];
        URd2 += XPp[((size_t)blk * 3 + 2) * 64 + c];
      }
      const float P0t = Wp2[c * 3 + 0], P1t = Wp2[c * 3 + 1], P2t = Wp2[c * 3 + 2];
      const float Nf = 512.f, invM = 1.f / 524288.f;
      float S1 = 0.f, Q2 = 0.f;
#pragma unroll
      for (int bb = 0; bb < 2; ++bb) {
        S1 += Nf * (Su[bb] - Sk[bb]);
        Q2 += Nf * Su2[bb] - 2.f * Su[bb] * Sk[bb] + Nf * Sk2[bb];
      }
      const float Xc = P0t * URd0 + P1t * URd1 + P2t * URd2;
      S1 += P0t * ShfS[0] + P1t * ShfS[1] + P2t * ShfS[2];
      const float Hm = P0t * P0t * MfS[0] + 2.f * P0t * P1t * MfS[1] + 2.f * P0t * P2t * MfS[2]
                     + P1t * P1t * MfS[3] + 2.f * P1t * P2t * MfS[4] + P2t * P2t * MfS[5];
      const float E1 = S1 * invM;
      const float E2 = (Q2 + 2.f * Xc + Hm) * invM;
      const float var = E2 - E1 * E1;
      const float rstd = rsqrtf(var + 1e-5f);
      const float A2 = g_w[c] * rstd;
      a2o[c] = A2;
      be2o[c] = b_w[c] - E1 * A2;
      PtT[0 * 64 + c] = A2 * P0t;
      PtT[1 * 64 + c] = A2 * P1t;
      PtT[2 * 64 + c] = A2 * P2t;
    }
  }
}

// ---------------------------------------------------------------------------
// k3: fused main (validated round-4 version, unchanged).
// ---------------------------------------------------------------------------
__launch_bounds__(256)
__global__ void k3_main(const float* __restrict__ q, const float* __restrict__ kk_,
                        const float* __restrict__ vT, const float* __restrict__ hpa,
                        const float* __restrict__ a2g, const float* __restrict__ be2g,
                        const float* __restrict__ PtTg,
                        const uint16_t* __restrict__ W1bf, const uint16_t* __restrict__ W2bf,
                        const float* __restrict__ bp2, const float* __restrict__ Wp2,
                        const float* __restrict__ b_p, const float* __restrict__ bw1g,
                        const float* __restrict__ bw2g, float* __restrict__ out) {
  const int bid = blockIdx.x;
  const int b = bid >> 9, i = bid & 511;
  const int t = threadIdx.x;
  const int wid = t >> 6, l = t & 63;
  const int lm = l & 15, lq = l >> 4;

  __shared__ __align__(16) uint16_t W1l[4096];
  __shared__ __align__(16) uint16_t W2l[4096];
  __shared__ __align__(16) uint16_t H2[4][16][76];
  __shared__ __align__(16) float P0[64];
  __shared__ __align__(16) float a2s[64];
  __shared__ __align__(16) float Pts[3][64];
  __shared__ __align__(16) float comb[4][64][2];

  {
    *(bf16x8*)(&W1l[t * 16])     = *(const bf16x8*)(W1bf + t * 16);
    *(bf16x8*)(&W1l[t * 16 + 8]) = *(const bf16x8*)(W1bf + t * 16 + 8);
    *(bf16x8*)(&W2l[t * 16])     = *(const bf16x8*)(W2bf + t * 16);
    *(bf16x8*)(&W2l[t * 16 + 8]) = *(const bf16x8*)(W2bf + t * 16 + 8);
  }
  if (t < 64) {
    const float a2v = a2g[t];
    a2s[t] = a2v;
    P0[t] = fmaf(a2v, q[(size_t)(b * 512 + i) * 64 + t] + bp2[t], be2g[t]);
  } else {
    const int idx = t - 64;
    Pts[idx >> 6][idx & 63] = PtTg[idx];
  }

  const f32x4 hi = *(const f32x4*)(hpa + (size_t)(b * 512 + i) * 4);
  const float bb0 = b_p[0], bb1 = b_p[1], bb2 = b_p[2];
  const float LOG2E = 1.4426950408889634f;

  float bw1r[4], bw2l[4], wpa[4], wpb[4], wpc[4];
#pragma unroll
  for (int nt = 0; nt < 4; ++nt) {
    const int c = 16 * nt + lm;
    bw1r[nt] = bw1g[c];
    bw2l[nt] = bw2g[c] * LOG2E;
    wpa[nt] = Wp2[c * 3 + 0];
    wpb[nt] = Wp2[c * 3 + 1];
    wpc[nt] = Wp2[c * 3 + 2];
  }

  float l_[4] = {0.f, 0.f, 0.f, 0.f};
  float acc_[4] = {0.f, 0.f, 0.f, 0.f};

  __syncthreads();

  const float* kbase = kk_ + (size_t)(b * 512) * 64;
  const float* hbase = hpa + (size_t)(b * 512) * 4;
  const float* vTb = vT + (size_t)b * 64 * 512;

  for (int it = 0; it < 8; ++it) {
    const int jb = it * 64 + wid * 16;
    const int j = jb + lm;
    const int j2 = jb + 4 * lq;

    f32x4 kv[2][2];
#pragma unroll
    for (int ks = 0; ks < 2; ++ks) {
      kv[ks][0] = *(const f32x4*)(kbase + (size_t)j * 64 + 32 * ks + 8 * lq);
      kv[ks][1] = *(const f32x4*)(kbase + (size_t)j * 64 + 32 * ks + 8 * lq + 4);
    }
    const f32x4 hj = *(const f32x4*)(hbase + j * 4);
    f32x4 hjr[4];
#pragma unroll
    for (int r = 0; r < 4; ++r) hjr[r] = *(const f32x4*)(hbase + (j2 + r) * 4);
    f32x4 vv[4];
#pragma unroll
    for (int nt = 0; nt < 4; ++nt)
      vv[nt] = *(const f32x4*)(vTb + (size_t)(16 * nt + lm) * 512 + j2);

    const float h0 = fmaxf(0.f, hi.x - hj.x + bb0);
    const float h1 = fmaxf(0.f, hi.y - hj.y + bb1);
    const float h2v = fmaxf(0.f, hi.z - hj.z + bb2);

    FragU A1[2];
#pragma unroll
    for (int ks = 0; ks < 2; ++ks) {
      const int c0 = 32 * ks + 8 * lq;
      f32x4 pv[2], av[2], t0[2], t1[2], t2[2];
      pv[0] = *(const f32x4*)(P0 + c0);        pv[1] = *(const f32x4*)(P0 + c0 + 4);
      av[0] = *(const f32x4*)(a2s + c0);       av[1] = *(const f32x4*)(a2s + c0 + 4);
      t0[0] = *(const f32x4*)(&Pts[0][c0]);    t0[1] = *(const f32x4*)(&Pts[0][c0 + 4]);
      t1[0] = *(const f32x4*)(&Pts[1][c0]);    t1[1] = *(const f32x4*)(&Pts[1][c0 + 4]);
      t2[0] = *(const f32x4*)(&Pts[2][c0]);    t2[1] = *(const f32x4*)(&Pts[2][c0 + 4]);
      float x[8];
#pragma unroll
      for (int e = 0; e < 8; ++e) {
        const int hh = e >> 2, e4 = e & 3;
        float xv = pv[hh][e4] - av[hh][e4] * kv[ks][hh][e4];
        xv = fmaf(t0[hh][e4], h0, xv);
        xv = fmaf(t1[hh][e4], h1, xv);
        xv = fmaf(t2[hh][e4], h2v, xv);
        x[e] = fmaxf(0.f, xv);
      }
      A1[ks].u[0] = pk_bf16(x[0], x[1]);
      A1[ks].u[1] = pk_bf16(x[2], x[3]);
      A1[ks].u[2] = pk_bf16(x[4], x[5]);
      A1[ks].u[3] = pk_bf16(x[6], x[7]);
    }

    f32x4 d1[4];
#pragma unroll
    for (int nt = 0; nt < 4; ++nt) {
      FragU b0, b1;
      b0.f = *(const bf16x8*)(&W1l[((nt * 2 + 0) * 64 + l) * 8]);
      b1.f = *(const bf16x8*)(&W1l[((nt * 2 + 1) * 64 + l) * 8]);
      f32x4 z = {0.f, 0.f, 0.f, 0.f};
      z = __builtin_amdgcn_mfma_f32_16x16x32_bf16(A1[0].f, b0.f, z, 0, 0, 0);
      z = __builtin_amdgcn_mfma_f32_16x16x32_bf16(A1[1].f, b1.f, z, 0, 0, 0);
      d1[nt] = z;
    }

    uint16_t (*h2w)[76] = H2[wid];
#pragma unroll
    for (int nt = 0; nt < 4; ++nt) {
      const float e0 = fmaxf(0.f, d1[nt][0] + bw1r[nt]);
      const float e1 = fmaxf(0.f, d1[nt][1] + bw1r[nt]);
      const float e2 = fmaxf(0.f, d1[nt][2] + bw1r[nt]);
      const float e3 = fmaxf(0.f, d1[nt][3] + bw1r[nt]);
      const uint32_t u01 = pk_bf16(e0, e1);
      const uint32_t u23 = pk_bf16(e2, e3);
      const int col = 16 * nt + lm;
      h2w[4 * lq + 0][col] = (uint16_t)(u01 & 0xffffu);
      h2w[4 * lq + 1][col] = (uint16_t)(u01 >> 16);
      h2w[4 * lq + 2][col] = (uint16_t)(u23 & 0xffffu);
      h2w[4 * lq + 3][col] = (uint16_t)(u23 >> 16);
    }

    FragU A2[2];
    A2[0].f = *(const bf16x8*)(&h2w[lm][8 * lq]);
    A2[1].f = *(const bf16x8*)(&h2w[lm][32 + 8 * lq]);

    f32x4 d2[4];
#pragma unroll
    for (int nt = 0; nt < 4; ++nt) {
      FragU b0, b1;
      b0.f = *(const bf16x8*)(&W2l[((nt * 2 + 0) * 64 + l) * 8]);
      b1.f = *(const bf16x8*)(&W2l[((nt * 2 + 1) * 64 + l) * 8]);
      f32x4 z = {0.f, 0.f, 0.f, 0.f};
      z = __builtin_amdgcn_mfma_f32_16x16x32_bf16(A2[0].f, b0.f, z, 0, 0, 0);
      z = __builtin_amdgcn_mfma_f32_16x16x32_bf16(A2[1].f, b1.f, z, 0, 0, 0);
      d2[nt] = z;
    }

    float hr0[4], hr1[4], hr2[4];
#pragma unroll
    for (int r = 0; r < 4; ++r) {
      hr0[r] = fmaxf(0.f, hi.x - hjr[r].x + bb0);
      hr1[r] = fmaxf(0.f, hi.y - hjr[r].y + bb1);
      hr2[r] = fmaxf(0.f, hi.z - hjr[r].z + bb2);
    }

#pragma unroll
    for (int nt = 0; nt < 4; ++nt) {
      float p[4], val[4];
#pragma unroll
      for (int r = 0; r < 4; ++r) {
        p[r] = __builtin_amdgcn_exp2f(fmaf(d2[nt][r], LOG2E, bw2l[nt]));
        float v0 = vv[nt][r];
        v0 = fmaf(wpa[nt], hr0[r], v0);
        v0 = fmaf(wpb[nt], hr1[r], v0);
        v0 = fmaf(wpc[nt], hr2[r], v0);
        val[r] = v0;
      }
      l_[nt] += (p[0] + p[1]) + (p[2] + p[3]);
      float a = acc_[nt];
      a = fmaf(p[0], val[0], a);
      a = fmaf(p[1], val[1], a);
      a = fmaf(p[2], val[2], a);
      a = fmaf(p[3], val[3], a);
      acc_[nt] = a;
    }
  }

#pragma unroll
  for (int nt = 0; nt < 4; ++nt) {
    l_[nt] += __shfl_xor(l_[nt], 16);
    acc_[nt] += __shfl_xor(acc_[nt], 16);
    l_[nt] += __shfl_xor(l_[nt], 32);
    acc_[nt] += __shfl_xor(acc_[nt], 32);
  }
  if (lq == 0) {
#pragma unroll
    for (int nt = 0; nt < 4; ++nt) {
      comb[wid][16 * nt + lm][0] = l_[nt];
      comb[wid][16 * nt + lm][1] = acc_[nt];
    }
  }
  __syncthreads();
  if (t < 64) {
    float L = 0.f, A = 0.f;
#pragma unroll
    for (int w = 0; w < 4; ++w) {
      L += comb[w][t][0];
      A += comb[w][t][1];
    }
    out[(size_t)(b * 512 + i) * 64 + t] = A / L;
  }
}

// ---------------------------------------------------------------------------
extern "C" void kernel_launch(void* const* d_in, const int* in_sizes, int n_in,
                              void* d_out, int out_size, void* d_ws, size_t ws_size,
                              hipStream_t stream) {
  (void)in_sizes; (void)n_in; (void)out_size; (void)ws_size;
  const float* pos = (const float*)d_in[0];
  const float* cf  = (const float*)d_in[1];
  const float* Wq  = (const float*)d_in[2];
  const float* bq  = (const float*)d_in[3];
  const float* Wk  = (const float*)d_in[4];
  const float* bk  = (const float*)d_in[5];
  const float* Wv  = (const float*)d_in[6];
  const float* bv  = (const float*)d_in[7];
  const float* Wp1 = (const float*)d_in[8];
  // d_in[9] = bp1: cancels analytically (gamma1 == b_p exactly)
  const float* g_p = (const float*)d_in[10];
  const float* b_p = (const float*)d_in[11];
  const float* Wp2 = (const float*)d_in[12];
  const float* bp2 = (const float*)d_in[13];
  const float* g_w = (const float*)d_in[14];
  const float* b_w = (const float*)d_in[15];
  const float* Ww1 = (const float*)d_in[16];
  const float* bw1 = (const float*)d_in[17];
  const float* Ww2 = (const float*)d_in[18];
  const float* bw2 = (const float*)d_in[19];

  char* ws = (char*)d_ws;
  uint16_t*     W1bf = (uint16_t*)(ws + 0);        // 8 KB
  uint16_t*     W2bf = (uint16_t*)(ws + 8192);     // 8 KB
  float*        a1w  = (float*)(ws + 16384);       // 16 B
  unsigned int* cnt  = (unsigned int*)(ws + 16640);
  float*        hpaw = (float*)(ws + 16896);       // [1024][4]
  float*        qw   = (float*)(ws + 33280);       // [1024][64]
  float*        kw   = (float*)(ws + 295424);      // [1024][64]
  float*        vTw  = (float*)(ws + 557568);      // [2][64][512]
  float*        Mpw  = (float*)(ws + 819712);      // [32][12]
  float*        XPpw = (float*)(ws + 821248);      // [32][3][64]
  float*        SNpw = (float*)(ws + 845824);      // [32][2][64]
  float*        a2w  = (float*)(ws + 862208);
  float*        be2w = (float*)(ws + 862464);
  float*        PtTw = (float*)(ws + 862720);      // [3][64]

  kP<<<dim3(258), dim3(256), 0, stream>>>(cf, pos, Wq, Wk, Wv, bq, bk, bv,
                                          Ww1, Ww2, Wp1, g_p, bp2,
                                          qw, kw, vTw, W1bf, W2bf, a1w, cnt);
  kB<<<dim3(32), dim3(256), 0, stream>>>(pos, a1w, Wp1, b_p, qw, kw, bp2,
                                         g_w, b_w, Wp2,
                                         hpaw, Mpw, XPpw, SNpw, cnt,
                                         a2w, be2w, PtTw);
  k3_main<<<dim3(1024), dim3(256), 0, stream>>>(qw, kw, vTw, hpaw, a2w, be2w, PtTw,
                                                W1bf, W2bf, bp2, Wp2, b_p, bw1, bw2,
                                                (float*)d_out);
}